// Round 13
// baseline (152.400 us; speedup 1.0000x reference)
//
#include <hip/hip_runtime.h>

// AFM layer, MI355X gfx950.
// out[b] = sum_p attn_p * s_p,  s_p = sum_d x[i,d]x[j,d]p[d]
// History: R7 62.8 | R8/R9 237 FAILED pipeline-spill | R10 79 FAILED
// sp-as-MFMA | R11 87 FAILED 4 waves/batch | R12 57.0 WIN 1 wave = 1 batch |
// R13 83 FAILED 2 live fx16 spill | R14 65 FAILED sp-dots before MFMA |
// R15 58.6 NULL latency cuts | R16 55.7 WIN b64->b128 | R17 56.5 NULL
// 1-wave blocks (residency ~2.5-3 waves/SIMD is cap-insensitive) |
// R18 57.4 NULL 2 batches/wave | R19 57.2 NULL setprio + valid-hoist.
// R20 (this round): the R8 pipeline CONCEPT, re-tried with the spill
// mechanism removed. Diagnosis: R8/R13 spilled while REPORTING VGPR=64 under
// launch_bounds(256,4) — allocator stuck at the 64-reg bucket and scratched
// the extra ~50 live regs instead of allocating 80-128. R17 proved real
// residency doesn't follow resource caps -> relaxing to launch_bounds(256,2)
// (VGPR cap 256) is free. Pipeline: PH1(t+1) = ds_read/prod/4-MFMA-issue/
// sp-dots-in-shadow runs while body t's C is in flight; PH2(t) = logit/exp2/
// acc consumes C one body late. MACROS (pure textual inline, no lambda
// ref-outs = R8's trigger), A/B ping-pong, ONE fx16 across the backedge,
// peak ~122 regs. Gates: WRITE <= ~4MB (no scratch), VGPR_Count ~128.
// Body internals byte-equivalent to R16 (proven ordering: sp-dots AFTER
// MFMA issues, single 4-deep chain, b128 LDS).
// LDS: 4 x 40 x 88 f16 = 28,160 B. Zero barriers (per-wave private slices).
// Pair coverage per batch (25 bodies, 780/800 slots):
//   t=1..15 : 32-rotation (nl,(nl+t)&31) all-valid (prod symmetric);
//   t=16    : half-rotation, nl<16;  t=17..24: uniform rows 32..39;
//   cleanup : 8-triangle of fields 32..39 (28 pairs, closed-form unrank).

typedef _Float16 f16;
typedef f16 f16x2 __attribute__((ext_vector_type(2)));
typedef f16 f16x4 __attribute__((ext_vector_type(4)));
typedef f16 f16x8 __attribute__((ext_vector_type(8)));
typedef float fx16 __attribute__((ext_vector_type(16)));

#define NF 40
#define NB 8192
#define STR 88   // f16 per LDS row (176 B): 16B-aligned b128 rows, uniform
                 // bank-group spread (3r+c mod 8) at granule level (R16)

union V8 { f16x8 v8; f16x4 v4[2]; f16x2 v2[4]; };

// ---- phase 1: ds_read xj, prod, issue 4-deep MFMA chain, sp-dots in its
// shadow (R14: sp-dots AFTER the MFMA issues). Writes Cd, spd. ----
#define AFM_PH1(Cd, spd, XI, JR)                                              \
    do {                                                                      \
        const f16* base_ = Xs + (JR) * STR + h8;                              \
        V8 p0_, p1_, p2_, p3_;                                                \
        p0_.v8 = (XI)[0] * *(const f16x8*)(base_);          /* ds_read_b128 */\
        p1_.v8 = (XI)[1] * *(const f16x8*)(base_ + 16);                       \
        p2_.v8 = (XI)[2] * *(const f16x8*)(base_ + 32);                       \
        p3_.v8 = (XI)[3] * *(const f16x8*)(base_ + 48);                       \
        Cd = __builtin_amdgcn_mfma_f32_32x32x16_f16(w1f[0], p0_.v8, b1C, 0, 0, 0); \
        Cd = __builtin_amdgcn_mfma_f32_32x32x16_f16(w1f[1], p1_.v8, Cd, 0, 0, 0);  \
        Cd = __builtin_amdgcn_mfma_f32_32x32x16_f16(w1f[2], p2_.v8, Cd, 0, 0, 0);  \
        Cd = __builtin_amdgcn_mfma_f32_32x32x16_f16(w1f[3], p3_.v8, Cd, 0, 0, 0);  \
        float s0_ = 0.f, s1_ = 0.f, s2_ = 0.f, s3_ = 0.f;                     \
        _Pragma("unroll")                                                     \
        for (int m_ = 0; m_ < 4; ++m_) {                                      \
            s0_ = __builtin_amdgcn_fdot2(p0_.v2[m_], pp[m_],      s0_, false);\
            s1_ = __builtin_amdgcn_fdot2(p1_.v2[m_], pp[4 + m_],  s1_, false);\
            s2_ = __builtin_amdgcn_fdot2(p2_.v2[m_], pp[8 + m_],  s2_, false);\
            s3_ = __builtin_amdgcn_fdot2(p3_.v2[m_], pp[12 + m_], s3_, false);\
        }                                                                     \
        spd = (s0_ + s1_) + (s2_ + s3_);                                      \
    } while (0)

// ---- phase 2: logit from C (one body late — MFMA latency elapsed),
// a-half combine, exp2, accumulate. ----
#define AFM_PH2(Cs, sps, VOK)                                                 \
    do {                                                                      \
        const f16x2 z2_ = { (f16)0.f, (f16)0.f };                             \
        float l0_ = 0.f, l1_ = 0.f;                                           \
        _Pragma("unroll")                                                     \
        for (int m_ = 0; m_ < 8; ++m_) {                                      \
            f16x2 hm_ = __builtin_bit_cast(f16x2,                             \
                __builtin_amdgcn_cvt_pkrtz((Cs)[2 * m_], (Cs)[2 * m_ + 1]));  \
            hm_ = __builtin_elementwise_max(hm_, z2_);     /* v_pk_max_f16 */ \
            if (m_ & 1) l1_ = __builtin_amdgcn_fdot2(hm_, w2h[m_], l1_, false);\
            else        l0_ = __builtin_amdgcn_fdot2(hm_, w2h[m_], l0_, false);\
        }                                                                     \
        float l_ = l0_ + l1_;                                                 \
        l_ += __shfl_xor(l_, 32);                          /* a-halves */     \
        float w_ = __builtin_amdgcn_exp2f(l_);             /* max-free SM */  \
        if (!(VOK)) w_ = 0.f;                                                 \
        accW += w_;                                                           \
        accWS = fmaf(w_, sps, accWS);                      /* k-half acc */   \
    } while (0)

__global__ __launch_bounds__(256, 2) void afm_kernel(
    const float* __restrict__ x,   // [8192,40,64]
    const float* __restrict__ W1,  // [64,32]
    const float* __restrict__ b1,  // [32]
    const float* __restrict__ w2,  // [32]
    const float* __restrict__ p,   // [64]
    float* __restrict__ out)       // [8192]
{
    __shared__ __align__(16) f16 xh[4][NF * STR];   // 28,160 B

    const int tid  = threadIdx.x;
    const int wid  = tid >> 6;          // wave -> private batch
    const int lane = tid & 63;
    const int b    = blockIdx.x * 4 + wid;

    f16* Xs = &xh[wid][0];

    // ---- per-wave staging: this wave's batch only (2560 floats) ----
    // 320 granules of 8 f16 = 5 x 64 lanes exact; zero barriers in kernel.
    const float4* xb = (const float4*)(x + (size_t)b * (NF * 64));
#pragma unroll
    for (int t = 0; t < 5; ++t) {
        int g = t * 64 + lane;                 // granule 0..319 (8 f16 each)
        float4 v0 = xb[g * 2];
        float4 v1 = xb[g * 2 + 1];
        V8 w;                                   // scalar RNE converts (x8)
        w.v4[0] = f16x4{ (f16)v0.x, (f16)v0.y, (f16)v0.z, (f16)v0.w };
        w.v4[1] = f16x4{ (f16)v1.x, (f16)v1.y, (f16)v1.z, (f16)v1.w };
        int row = g >> 3, gg = g & 7;
        *(f16x8*)(Xs + row * STR + gg * 8) = w.v8;   // ds_write_b128
    }

    const int nl = lane & 31;   // MFMA column / field index base
    const int hh = lane >> 5;   // wave half -> k sub-block + a-row group
    const int h8 = hh * 8;

    // ---- A-frags: W1^T, A[m=a][k=h8+j], d = kt*16 + h8 + j ----
    f16x8 w1f[4];
#pragma unroll
    for (int kt = 0; kt < 4; ++kt)
#pragma unroll
        for (int j = 0; j < 8; ++j)
            w1f[kt][j] = (f16)W1[(kt * 16 + h8 + j) * 32 + nl];

    // ---- p packed to match prod-frag element order (for fdot2) ----
    f16x2 pp[16];
#pragma unroll
    for (int kt = 0; kt < 4; ++kt)
#pragma unroll
        for (int m = 0; m < 4; ++m) {
            f16x2 t2 = { (f16)p[kt * 16 + h8 + 2 * m], (f16)p[kt * 16 + h8 + 2 * m + 1] };
            pp[kt * 4 + m] = t2;
        }

    // ---- b1 as persistent C-frag; w2*log2e packed f16 (exp2 direct) ----
    fx16 b1C;
    f16x2 w2h[8];
#pragma unroll
    for (int r = 0; r < 16; ++r) {
        int a = (r & 3) + 8 * (r >> 2) + 4 * hh;
        b1C[r] = b1[a];
    }
#pragma unroll
    for (int m = 0; m < 8; ++m) {
        int r = 2 * m;
        int a = (r & 3) + 8 * (r >> 2) + 4 * hh;
        f16x2 t2 = { (f16)(w2[a] * 1.44269504f), (f16)(w2[a + 1] * 1.44269504f) };
        w2h[m] = t2;
    }

    // ---- xi frags for row nl: 4 x ds_read_b128 ----
    f16x8 xif8[4];
    {
        const f16* src = Xs + nl * STR + h8;
#pragma unroll
        for (int kt = 0; kt < 4; ++kt)
            xif8[kt] = *(const f16x8*)(src + kt * 16);
    }

    float accW = 0.f, accWS = 0.f;   // accWS = k-HALF sums (combined at end)

    // ---- 1-deep pipelined schedule: A/B ping-pong, macro-inlined ----
    fx16 CA, CB;
    float spA, spB;
    bool vA, vB;

    AFM_PH1(CA, spA, xif8, (nl + 1) & 31); vA = true;        // t = 1
#pragma unroll 1
    for (int k = 0; k < 11; ++k) {                           // t = 2..23
        const int t1 = 2 + 2 * k, t2 = 3 + 2 * k;
        const int j1 = (t1 <= 16) ? ((nl + t1) & 31) : (t1 + 15);
        AFM_PH1(CB, spB, xif8, j1); vB = (t1 != 16) || (nl < 16);
        AFM_PH2(CA, spA, vA);
        const int j2 = (t2 <= 16) ? ((nl + t2) & 31) : (t2 + 15);
        AFM_PH1(CA, spA, xif8, j2); vA = (t2 != 16) || (nl < 16);
        AFM_PH2(CB, spB, vB);
    }
    AFM_PH1(CB, spB, xif8, 39); vB = true;                   // t = 24
    AFM_PH2(CA, spA, vA);
    {   // cleanup: 28 pairs among fields 32..39 (lanes nl<28)
        int q = nl < 28 ? nl : 27;
        float disc = 225.0f - 8.0f * (float)q;
        int ii = (int)((15.0f - sqrtf(disc)) * 0.5f);
        if (ii * (15 - ii) / 2 > q) --ii;                 // sqrt 1-ulp fixups
        if ((ii + 1) * (14 - ii) / 2 <= q) ++ii;
        int jj = q - ii * (15 - ii) / 2 + ii + 1;
        int iC = 32 + ii, jC = 32 + jj;                   // pair (iC,jC), iC<jC
        f16x8 xi2[4];
        const f16* src = Xs + iC * STR + h8;
#pragma unroll
        for (int kt = 0; kt < 4; ++kt)
            xi2[kt] = *(const f16x8*)(src + kt * 16);
        AFM_PH1(CA, spA, xi2, jC); vA = (nl < 28);
        AFM_PH2(CB, spB, vB);
        AFM_PH2(CA, spA, vA);
    }

    // combine k-halves ONCE, then 32-column butterfly
    accWS += __shfl_xor(accWS, 32);
#pragma unroll
    for (int m = 16; m >= 1; m >>= 1) {
        accW  += __shfl_xor(accW, m);
        accWS += __shfl_xor(accWS, m);
    }
    if (lane == 0) out[b] = accWS / accW;
}

extern "C" void kernel_launch(void* const* d_in, const int* in_sizes, int n_in,
                              void* d_out, int out_size, void* d_ws, size_t ws_size,
                              hipStream_t stream) {
    const float* x  = (const float*)d_in[0];
    const float* W1 = (const float*)d_in[1];
    const float* b1 = (const float*)d_in[2];
    const float* w2 = (const float*)d_in[3];
    const float* p  = (const float*)d_in[4];
    float* out = (float*)d_out;
    dim3 grid(NB / 4), block(256);
    hipLaunchKernelGGL(afm_kernel, grid, block, 0, stream, x, W1, b1, w2, p, out);
}

// Round 14
// 149.319 us; speedup vs baseline: 1.0206x; 1.0206x over previous
//
#include <hip/hip_runtime.h>

// AFM layer, MI355X gfx950 — FINAL (R21 = R16 revert, best measured).
// out[b] = sum_p attn_p * s_p,  s_p = sum_d x[i,d]x[j,d]p[d]
// Session ledger: R7 62.8 (2 waves/batch) | R8/R9 237 FAILED pipeline via
// lambda ref-outs -> scratch | R10 79 FAILED sp-as-2nd-MFMA-chain | R11 87
// FAILED 4 waves/batch | R12 57.0 WIN 1 wave = 1 batch, 0 barriers, setup
// amortized over 25 bodies | R13 83 FAILED 2 live fx16 -> spill | R14 65
// FAILED sp-dots hoisted before MFMA issue | R15 58.6 NULL terminal-latency
// cuts | R16 55.7 WIN b64->b128 (STR 88, 0 conflicts) | R17 56.5 NULL 1-wave
// blocks | R18 57.4 NULL 2 batches/wave | R19 57.2 NULL setprio+valid-hoist |
// R20 60.2 NULL/NEG honest pipeline (VGPR 84, no spill — still slower;
// occupancy 32->26%).
// FLOOR STATEMENT: per-body VALU is algorithmically minimal (~56: prod 16
// pk_mul, sp 16 fdot2, logit 24 packed). Issue-work deletion was the only
// paying lever (elasticity ~0.4) and is spent. Remaining headroom is locked
// behind wave residency pinned at ~2.5-3/SIMD (occ 26-33% under EVERY
// packaging/VGPR/priority configuration tried; rises for nothing, falls
// with added per-wave state). Not a memory/compute roofline (HBM 9%, MFMA
// 19%, VALU 52%) — a scheduler-residency floor for 8192 tiny independent
// reductions of ~4k serial cycles each.
// Structure: 1 wave = 1 batch (4/block), zero barriers, per-wave-private
// LDS slice; x staged f32->f16 into STR=88 rows (176B, 16B-aligned ->
// ds_*_b128 everywhere; bank-groups (3r+c)%8 uniform; MEASURED 0 conflicts);
// body = 4x{ds_read_b128, pk_mul} -> single 4-deep 32x32x16 MFMA chain
// (C-init = persistent b1 frag; ONE live fx16 — two spills, R13) -> sp
// fdot2 trees in the MFMA shadow (AFTER issue — R14) -> packed-f16 logit
// (cvt_pkrtz + pk_max + fdot2, w2 pre-scaled by log2e -> exp2 direct,
// max-free softmax) -> accW/accWS (k-half sums; single end shfl).
// Pair coverage per batch (25 bodies, 780/800 slots):
//   t=1..15 : 32-rotation (nl,(nl+t)&31) all-valid (prod symmetric);
//   t=16    : half-rotation, nl<16;  t=17..24: uniform rows 32..39;
//   cleanup : 8-triangle of fields 32..39 (28 pairs, closed-form unrank).
// __launch_bounds__(256,4): lands at VGPR 64, no spill (proven R12-R19).

typedef _Float16 f16;
typedef f16 f16x2 __attribute__((ext_vector_type(2)));
typedef f16 f16x4 __attribute__((ext_vector_type(4)));
typedef f16 f16x8 __attribute__((ext_vector_type(8)));
typedef float fx16 __attribute__((ext_vector_type(16)));

#define NF 40
#define NB 8192
#define STR 88   // f16 per LDS row (176 B): 16B-aligned b128 rows, uniform
                 // bank-group spread (3r+c mod 8) at granule level (R16)

union V8 { f16x8 v8; f16x4 v4[2]; f16x2 v2[4]; };

__global__ __launch_bounds__(256, 4) void afm_kernel(
    const float* __restrict__ x,   // [8192,40,64]
    const float* __restrict__ W1,  // [64,32]
    const float* __restrict__ b1,  // [32]
    const float* __restrict__ w2,  // [32]
    const float* __restrict__ p,   // [64]
    float* __restrict__ out)       // [8192]
{
    __shared__ __align__(16) f16 xh[4][NF * STR];   // 28,160 B

    const int tid  = threadIdx.x;
    const int wid  = tid >> 6;          // wave -> private batch
    const int lane = tid & 63;
    const int b    = blockIdx.x * 4 + wid;

    f16* Xs = &xh[wid][0];

    // ---- per-wave staging: this wave's batch only (2560 floats) ----
    // 320 granules of 8 f16 = 5 x 64 lanes exact; zero barriers in kernel.
    const float4* xb = (const float4*)(x + (size_t)b * (NF * 64));
#pragma unroll
    for (int t = 0; t < 5; ++t) {
        int g = t * 64 + lane;                 // granule 0..319 (8 f16 each)
        float4 v0 = xb[g * 2];
        float4 v1 = xb[g * 2 + 1];
        V8 w;                                   // scalar RNE converts (x8)
        w.v4[0] = f16x4{ (f16)v0.x, (f16)v0.y, (f16)v0.z, (f16)v0.w };
        w.v4[1] = f16x4{ (f16)v1.x, (f16)v1.y, (f16)v1.z, (f16)v1.w };
        int row = g >> 3, gg = g & 7;
        *(f16x8*)(Xs + row * STR + gg * 8) = w.v8;   // ds_write_b128
    }

    const int nl = lane & 31;   // MFMA column / field index base
    const int hh = lane >> 5;   // wave half -> k sub-block + a-row group
    const int h8 = hh * 8;

    // ---- A-frags: W1^T, A[m=a][k=h8+j], d = kt*16 + h8 + j ----
    f16x8 w1f[4];
#pragma unroll
    for (int kt = 0; kt < 4; ++kt)
#pragma unroll
        for (int j = 0; j < 8; ++j)
            w1f[kt][j] = (f16)W1[(kt * 16 + h8 + j) * 32 + nl];

    // ---- p packed to match prod-frag element order (for fdot2) ----
    f16x2 pp[16];
#pragma unroll
    for (int kt = 0; kt < 4; ++kt)
#pragma unroll
        for (int m = 0; m < 4; ++m) {
            f16x2 t2 = { (f16)p[kt * 16 + h8 + 2 * m], (f16)p[kt * 16 + h8 + 2 * m + 1] };
            pp[kt * 4 + m] = t2;
        }

    // ---- b1 as persistent C-frag; w2*log2e packed f16 (exp2 direct) ----
    fx16 b1C;
    f16x2 w2h[8];
#pragma unroll
    for (int r = 0; r < 16; ++r) {
        int a = (r & 3) + 8 * (r >> 2) + 4 * hh;
        b1C[r] = b1[a];
    }
#pragma unroll
    for (int m = 0; m < 8; ++m) {
        int r = 2 * m;
        int a = (r & 3) + 8 * (r >> 2) + 4 * hh;
        f16x2 t2 = { (f16)(w2[a] * 1.44269504f), (f16)(w2[a + 1] * 1.44269504f) };
        w2h[m] = t2;
    }

    // ---- xi frags for row nl: 4 x ds_read_b128 ----
    f16x8 xif8[4];
    {
        const f16* src = Xs + nl * STR + h8;
#pragma unroll
        for (int kt = 0; kt < 4; ++kt)
            xif8[kt] = *(const f16x8*)(src + kt * 16);
    }

    float accW = 0.f, accWS = 0.f;   // accWS = k-HALF sums (combined at end)

    auto body = [&](const f16x8* xi, int jrow, bool valid) {
        const f16* base = Xs + jrow * STR + h8;
        V8 pr[4];
#pragma unroll
        for (int kt = 0; kt < 4; ++kt) {
            f16x8 xj = *(const f16x8*)(base + kt * 16);        // ds_read_b128
            pr[kt].v8 = xi[kt] * xj;                           // v_pk_mul_f16 x4
        }
        // h = W1^T prod + b1 : single 4-deep chain from persistent b1 frag
        fx16 C = __builtin_amdgcn_mfma_f32_32x32x16_f16(w1f[0], pr[0].v8, b1C, 0, 0, 0);
        C = __builtin_amdgcn_mfma_f32_32x32x16_f16(w1f[1], pr[1].v8, C, 0, 0, 0);
        C = __builtin_amdgcn_mfma_f32_32x32x16_f16(w1f[2], pr[2].v8, C, 0, 0, 0);
        C = __builtin_amdgcn_mfma_f32_32x32x16_f16(w1f[3], pr[3].v8, C, 0, 0, 0);
        // s_p partial: 4 parallel fdot2 trees — in the MFMA shadow
        // (R14 lesson: AFTER the MFMA issues, not before)
        float s0 = 0.f, s1 = 0.f, s2 = 0.f, s3 = 0.f;
#pragma unroll
        for (int m = 0; m < 4; ++m) {
            s0 = __builtin_amdgcn_fdot2(pr[0].v2[m], pp[m],      s0, false);
            s1 = __builtin_amdgcn_fdot2(pr[1].v2[m], pp[4 + m],  s1, false);
            s2 = __builtin_amdgcn_fdot2(pr[2].v2[m], pp[8 + m],  s2, false);
            s3 = __builtin_amdgcn_fdot2(pr[3].v2[m], pp[12 + m], s3, false);
        }
        float sp = (s0 + s1) + (s2 + s3);                      // k-half sum
        // logit partial: relu(h).(w2*log2e) in packed f16, 2 parallel trees
        const f16x2 z2 = { (f16)0.f, (f16)0.f };
        float l0 = 0.f, l1 = 0.f;
#pragma unroll
        for (int m = 0; m < 8; ++m) {
            f16x2 hm = __builtin_bit_cast(f16x2,
                __builtin_amdgcn_cvt_pkrtz(C[2 * m], C[2 * m + 1]));
            hm = __builtin_elementwise_max(hm, z2);            // v_pk_max_f16
            if (m & 1) l1 = __builtin_amdgcn_fdot2(hm, w2h[m], l1, false);
            else       l0 = __builtin_amdgcn_fdot2(hm, w2h[m], l0, false);
        }
        float l = l0 + l1;
        l += __shfl_xor(l, 32);     // combine a-halves
        float w = __builtin_amdgcn_exp2f(l);   // max-free softmax (|l| small)
        if (!valid) w = 0.f;
        accW += w;
        accWS = fmaf(w, sp, accWS);            // k-half accumulate (no shfl)
    };

    // all 24 rotation/uniform bodies + cleanup: this wave's batch, private
    for (int t = 1; t <= 24; ++t) {
        int jrow = (t <= 16) ? ((nl + t) & 31) : (t + 15);
        bool valid = (t != 16) || (nl < 16);
        body(xif8, jrow, valid);
    }
    {   // cleanup: 28 pairs among fields 32..39 (lanes nl<28)
        int q = nl < 28 ? nl : 27;
        float disc = 225.0f - 8.0f * (float)q;
        int ii = (int)((15.0f - sqrtf(disc)) * 0.5f);
        if (ii * (15 - ii) / 2 > q) --ii;                 // sqrt 1-ulp fixups
        if ((ii + 1) * (14 - ii) / 2 <= q) ++ii;
        int jj = q - ii * (15 - ii) / 2 + ii + 1;
        int iC = 32 + ii, jC = 32 + jj;                   // pair (iC,jC), iC<jC
        f16x8 xi2[4];
        const f16* src = Xs + iC * STR + h8;
#pragma unroll
        for (int kt = 0; kt < 4; ++kt)
            xi2[kt] = *(const f16x8*)(src + kt * 16);
        body(xi2, jC, nl < 28);
    }

    // combine k-halves ONCE, then 32-column butterfly
    accWS += __shfl_xor(accWS, 32);
#pragma unroll
    for (int m = 16; m >= 1; m >>= 1) {
        accW  += __shfl_xor(accW, m);
        accWS += __shfl_xor(accWS, m);
    }
    if (lane == 0) out[b] = accWS / accW;
}

extern "C" void kernel_launch(void* const* d_in, const int* in_sizes, int n_in,
                              void* d_out, int out_size, void* d_ws, size_t ws_size,
                              hipStream_t stream) {
    const float* x  = (const float*)d_in[0];
    const float* W1 = (const float*)d_in[1];
    const float* b1 = (const float*)d_in[2];
    const float* w2 = (const float*)d_in[3];
    const float* p  = (const float*)d_in[4];
    float* out = (float*)d_out;
    dim3 grid(NB / 4), block(256);
    hipLaunchKernelGGL(afm_kernel, grid, block, 0, stream, x, W1, b1, w2, p, out);
}